// Round 7
// baseline (3656.495 us; speedup 1.0000x reference)
//
#include <hip/hip_runtime.h>

#define F_ 513
#define M_ 8
#define T_ 2048
#define K_ 2
#define NITER 20
#define REGC 1e-6
#define EPSR 1e-10
#define TOLC 1e-5
#define TS 4

typedef double2 cd;
__device__ __forceinline__ cd cmk(double r, double i){ cd z; z.x=r; z.y=i; return z; }
__device__ __forceinline__ cd cadd(cd a, cd b){ return cmk(a.x+b.x, a.y+b.y); }
__device__ __forceinline__ cd csub(cd a, cd b){ return cmk(a.x-b.x, a.y-b.y); }
__device__ __forceinline__ cd cmul(cd a, cd b){ return cmk(a.x*b.x - a.y*b.y, a.x*b.y + a.y*b.x); }
__device__ __forceinline__ cd cconj(cd a){ return cmk(a.x, -a.y); }
__device__ __forceinline__ cd cdiv(cd a, cd b){
  double d = b.x*b.x + b.y*b.y;
  return cmk((a.x*b.x + a.y*b.y)/d, (a.y*b.x - a.x*b.y)/d);
}
__device__ __forceinline__ double cabs2(cd a){ return a.x*a.x + a.y*a.y; }
__device__ __forceinline__ cd shflc(cd v, int l){
  cd r; r.x = __shfl(v.x, l, 64); r.y = __shfl(v.y, l, 64); return r;
}
__device__ __forceinline__ cd sel8(const cd x[8], int idx){
  cd r = x[0];
  #pragma unroll
  for (int q=1;q<8;++q) if (idx==q) r = x[q];
  return r;
}

// pack X (M,T,F,2) -> Xc (F,M,T) complex; 64f x 32t LDS tile (16.6 KB -> high occupancy)
__global__ __launch_bounds__(256) void pack_kernel(const float2* __restrict__ Xin, float2* __restrict__ Xc){
  __shared__ float tr[32][65];
  __shared__ float ti[32][65];
  int f0 = blockIdx.x*64, t0 = blockIdx.y*32, m = blockIdx.z;
  for (int i = threadIdx.x; i < 32*64; i += 256){
    int tl = i >> 6, fl = i & 63;      // lanes -> consecutive f (coalesced read)
    int f = f0 + fl;
    float2 v; v.x = 0.f; v.y = 0.f;
    if (f < F_) v = Xin[((size_t)m*T_ + (t0 + tl))*F_ + f];
    tr[tl][fl] = v.x; ti[tl][fl] = v.y;
  }
  __syncthreads();
  for (int i = threadIdx.x; i < 64*16; i += 256){
    int fl = i >> 4, tl2 = i & 15;     // float4 writes, t-contiguous
    int f = f0 + fl;
    if (f < F_){
      int t = 2*tl2;
      float4 v;
      v.x = tr[t][fl];   v.y = ti[t][fl];
      v.z = tr[t+1][fl]; v.w = ti[t+1][fl];
      *(float4*)&Xc[((size_t)f*8 + m)*T_ + t0 + t] = v;
    }
  }
}

__global__ __launch_bounds__(256) void winit_kernel(float2* __restrict__ W){
  int idx = blockIdx.x*256 + threadIdx.x;
  if (idx >= F_*64) return;
  int l = idx & 63; int i = l>>3, j = l&7;
  float v = (i==j) ? (i < K_ ? 1.f : -1.f) : 0.f;
  float2 o; o.x = v; o.y = 0.f;
  W[idx] = o;
}

// C partials (grid (F,TS), 512 thr) + initial part[f][t] = (|x0|^2, |x1|^2)
// (initial W rows 0,1 are e0,e1, so Y=X[:2] exactly)
__global__ __launch_bounds__(512) void cov0_kernel(const float2* __restrict__ Xc, cd* __restrict__ Cp,
                                                   float2* __restrict__ part){
  __shared__ float2 xs[8][514];
  __shared__ double wred[2][8][64];
  int f = blockIdx.x, s = blockIdx.y;
  int tid = threadIdx.x;
  int w = tid >> 6, lane = tid & 63;
  int m = lane >> 3, n = lane & 7;
  #pragma unroll
  for (int r=0; r<4; ++r){
    int idx = tid + r*512;
    int mm = idx >> 8, q = idx & 255;
    float4 v = ((const float4*)(Xc + ((size_t)f*8 + mm)*T_ + s*512))[q];
    *(float4*)&xs[mm][q*2] = v;
  }
  __syncthreads();
  {
    float2 x0 = xs[0][tid], x1 = xs[1][tid];
    part[(size_t)f*T_ + s*512 + tid] =
      make_float2(fmaf(x0.x,x0.x,x0.y*x0.y), fmaf(x1.x,x1.x,x1.y*x1.y));
  }
  const float2* xm = xs[m];
  const float2* xn = xs[n];
  int tbase = w*64;
  float ar=0.f, ai=0.f;
  #pragma unroll 8
  for (int tt=0; tt<64; tt+=2){
    float4 av = *(const float4*)&xm[tbase+tt];
    float4 bv = *(const float4*)&xn[tbase+tt];
    ar += fmaf(av.x, bv.x, av.y*bv.y) + fmaf(av.z, bv.z, av.w*bv.w);
    ai += fmaf(av.y, bv.x, -av.x*bv.y) + fmaf(av.w, bv.z, -av.z*bv.w);
  }
  wred[0][w][lane] = ar; wred[1][w][lane] = ai;
  __syncthreads();
  if (tid < 64){
    double sr=0, si=0;
    #pragma unroll
    for (int ww=0; ww<8; ++ww){ sr += wred[0][ww][tid]; si += wred[1][ww][tid]; }
    const double inv = 1.0/(double)T_;
    Cp[((size_t)f*TS + s)*64 + tid] = cmk(sr*inv, si*inv);
  }
}

// wts2[t] = (0.5/sqrt(max(sum_f part[f][t].x,eps)), same for .y); 32 blocks x 512 thr
__global__ __launch_bounds__(512) void rw_kernel(const float2* __restrict__ part, float2* __restrict__ wts2,
                                                 const int* __restrict__ flags){
  if (*(volatile const int*)flags) return;
  __shared__ double wred[8][64][2];
  int tid = threadIdx.x;
  int w = tid >> 6, lane = tid & 63;
  int t = blockIdx.x*64 + lane;
  double s0=0, s1=0;
  for (int f=w; f<F_; f+=8){
    float2 p = part[(size_t)f*T_ + t];
    s0 += (double)p.x; s1 += (double)p.y;
  }
  wred[w][lane][0]=s0; wred[w][lane][1]=s1;
  __syncthreads();
  if (tid < 64){
    double a=0,b=0;
    #pragma unroll
    for (int ww=0; ww<8; ++ww){ a += wred[ww][tid][0]; b += wred[ww][tid][1]; }
    wts2[blockIdx.x*64 + tid] =
      make_float2((float)(0.5/sqrt(fmax(a,EPSR))), (float)(0.5/sqrt(fmax(b,EPSR))));
  }
}

// Fused per-f kernel: V (all chunks) -> wave0 solve+J -> new-W |Y|^2 partials.
// grid F_ blocks, 512 threads. Convergence via 513-block ticket.
__global__ __launch_bounds__(512, 4) void covupd_kernel(
    const float2* __restrict__ Xc, const float2* __restrict__ wts2,
    const cd* __restrict__ Cp, float2* __restrict__ Wg,
    float2* __restrict__ part, double* __restrict__ dsum, double* __restrict__ osum,
    int* __restrict__ flags, int do_yr)
{
  if (*(volatile const int*)flags) return;
  __shared__ float2 xs[8][514];
  __shared__ float2 wsm2[512];
  __shared__ double wred[4][8][64];
  __shared__ double Vd[2][64][2];
  __shared__ cd Cl[64];
  __shared__ cd Wl[64];
  __shared__ int lastF;
  int f = blockIdx.x;
  int tid = threadIdx.x;
  int w = tid >> 6, lane = tid & 63;
  int m = lane >> 3, n = lane & 7;
  double va0r=0, va0i=0, va1r=0, va1i=0;
  for (int s=0; s<TS; ++s){
    if (s) __syncthreads();
    #pragma unroll
    for (int r=0; r<4; ++r){
      int idx = tid + r*512;
      int mm = idx >> 8, q = idx & 255;
      float4 v = ((const float4*)(Xc + ((size_t)f*8 + mm)*T_ + s*512))[q];
      *(float4*)&xs[mm][q*2] = v;
    }
    wsm2[tid] = wts2[s*512 + tid];
    __syncthreads();
    const float2* xm = xs[m];
    const float2* xn = xs[n];
    int tbase = w*64;
    float a0r=0.f, a0i=0.f, a1r=0.f, a1i=0.f;
    #pragma unroll 8
    for (int tt=0; tt<64; tt+=2){
      float4 av = *(const float4*)&xm[tbase+tt];
      float4 bv = *(const float4*)&xn[tbase+tt];
      float zr0 = fmaf(av.x, bv.x, av.y*bv.y);
      float zi0 = fmaf(av.y, bv.x, -av.x*bv.y);
      float zr1 = fmaf(av.z, bv.z, av.w*bv.w);
      float zi1 = fmaf(av.w, bv.z, -av.z*bv.w);
      float4 wv = *(const float4*)&wsm2[tbase+tt];
      a0r = fmaf(wv.x, zr0, a0r); a0i = fmaf(wv.x, zi0, a0i);
      a1r = fmaf(wv.y, zr0, a1r); a1i = fmaf(wv.y, zi0, a1i);
      a0r = fmaf(wv.z, zr1, a0r); a0i = fmaf(wv.z, zi1, a0i);
      a1r = fmaf(wv.w, zr1, a1r); a1i = fmaf(wv.w, zi1, a1i);
    }
    va0r += a0r; va0i += a0i; va1r += a1r; va1i += a1i;
  }
  wred[0][w][lane] = va0r;
  wred[1][w][lane] = va0i;
  wred[2][w][lane] = va1r;
  wred[3][w][lane] = va1i;
  __syncthreads();
  if (tid < 256){
    int q = tid >> 6, l = tid & 63;
    double ssum = 0;
    #pragma unroll
    for (int ww=0; ww<8; ++ww) ssum += wred[q][ww][l];
    Vd[q>>1][l][q&1] = ssum * (1.0/(double)T_);
  } else if (tid < 320){
    int l = tid - 256;
    cd c = cmk(0,0);
    #pragma unroll
    for (int s2=0; s2<TS; ++s2) c = cadd(c, Cp[((size_t)f*TS + s2)*64 + l]);
    Cl[l] = c;
  }
  __syncthreads();
  if (w == 0){
    // ---- wave 0: solves + J (fp64, in-wave 8x8 layout) ----
    int i = lane >> 3, j = lane & 7;
    float2 wf = Wg[(size_t)f*64 + lane];
    cd Wn = cmk(wf.x, wf.y);
    cd Wold = Wn;
    cd x[8];
    #pragma unroll
    for (int k=0; k<K_; ++k){
      cd Vr = cmk(Vd[k][lane][0], Vd[k][lane][1]);
      if (i == j) Vr.x += REGC;
      cd temp = cmk(0,0);
      #pragma unroll
      for (int q=0;q<8;++q) temp = cadd(temp, cmul(shflc(Wn, i*8+q), shflc(Vr, q*8+j)));
      cd b = cmk(i==k ? 1.0 : 0.0, 0.0);
      for (int p=0; p<8; ++p){
        double pv = (j==p && i>=p) ? cabs2(temp) : -1.0;
        int pidx = i;
        for (int off=32; off; off>>=1){
          double ov = __shfl_xor(pv, off, 64);
          int oi = __shfl_xor(pidx, off, 64);
          if (ov > pv){ pv = ov; pidx = oi; }
        }
        cd tp = shflc(temp, pidx*8 + j);
        cd tq = shflc(temp, p*8 + j);
        cd bp_ = shflc(b, pidx*8 + j);
        cd bq_ = shflc(b, p*8 + j);
        if (i == p){ temp = tp; b = bp_; }
        else if (i == pidx){ temp = tq; b = bq_; }
        cd tip = shflc(temp, i*8 + p);
        cd tpp = shflc(temp, p*8 + p);
        cd tpj = shflc(temp, p*8 + j);
        cd bpr = shflc(b, p*8 + j);
        cd fac = cdiv(tip, tpp);
        if (i > p){ temp = csub(temp, cmul(fac, tpj)); b = csub(b, cmul(fac, bpr)); }
      }
      #pragma unroll
      for (int p=7; p>=0; --p){
        cd s = shflc(b, p*8);
        #pragma unroll
        for (int q=p+1; q<8; ++q){
          cd tpq = shflc(temp, p*8 + q);
          s = csub(s, cmul(tpq, x[q]));
        }
        x[p] = cdiv(s, shflc(temp, p*8 + p));
      }
      cd xi = sel8(x, i), xj = sel8(x, j);
      cd z = cmul(cconj(xi), Vr);
      double dl = z.x*xj.x - z.y*xj.y;
      for (int off=32; off; off>>=1) dl += __shfl_xor(dl, off, 64);
      double denom = sqrt(dl + EPSR);
      if (i == k){ Wn = cmk(xj.x/denom, -xj.y/denom); }
    }
    cd Cc = Cl[lane];
    cd tmp = cmk(0,0);
    #pragma unroll
    for (int q=0;q<8;++q) tmp = cadd(tmp, cmul(shflc(Wn, i*8+q), shflc(Cc, q*8+j)));
    cd A = shflc(tmp, 0), B = shflc(tmp, 1), C2 = shflc(tmp, 8), D = shflc(tmp, 9);
    cd det = csub(cmul(A,D), cmul(B,C2));
    cd t0 = shflc(tmp, i);
    cd t1 = shflc(tmp, 8 + i);
    cd Z0 = cdiv(csub(cmul(D,t0), cmul(B,t1)), det);
    cd Z1 = cdiv(csub(cmul(A,t1), cmul(C2,t0)), det);
    if (i >= K_ && j < K_){
      cd Z = (j==0) ? Z0 : Z1;
      Wn = cconj(Z);
    }
    double ds = cabs2(csub(Wn, Wold));
    double os = cabs2(Wold);
    for (int off=32; off; off>>=1){
      ds += __shfl_xor(ds, off, 64);
      os += __shfl_xor(os, off, 64);
    }
    Wl[lane] = Wn;
    float2 wo; wo.x = (float)Wn.x; wo.y = (float)Wn.y;
    Wg[(size_t)f*64 + lane] = wo;
    if (lane == 0){ dsum[f] = ds; osum[f] = os; }
  } else if (do_yr){
    // waves 1-7: pre-stage chunk 0 while wave 0 solves (hides solve latency)
    for (int idx = tid - 64; idx < 2048; idx += 448){
      int mm = idx >> 8, q = idx & 255;
      float4 v = ((const float4*)(Xc + ((size_t)f*8 + mm)*T_))[q];
      *(float4*)&xs[mm][q*2] = v;
    }
  }
  __syncthreads();
  if (do_yr){
    // ---- |Y|^2 with NEW W (rows 0,1) -> part[f][t] ----
    float2 w0f[8], w1f[8];
    #pragma unroll
    for (int mm=0;mm<8;++mm){
      cd c0 = Wl[mm], c1 = Wl[8+mm];
      w0f[mm] = make_float2((float)c0.x, (float)c0.y);
      w1f[mm] = make_float2((float)c1.x, (float)c1.y);
    }
    for (int s=0; s<TS; ++s){
      if (s){
        __syncthreads();
        #pragma unroll
        for (int r=0; r<4; ++r){
          int idx = tid + r*512;
          int mm = idx >> 8, q = idx & 255;
          float4 v = ((const float4*)(Xc + ((size_t)f*8 + mm)*T_ + s*512))[q];
          *(float4*)&xs[mm][q*2] = v;
        }
        __syncthreads();
      }
      float2 y0 = make_float2(0.f,0.f), y1 = make_float2(0.f,0.f);
      #pragma unroll
      for (int mm=0;mm<8;++mm){
        float2 xv = xs[mm][tid];
        float2 a = w0f[mm], b = w1f[mm];
        y0.x = fmaf(a.x,xv.x,fmaf(-a.y,xv.y,y0.x)); y0.y = fmaf(a.x,xv.y,fmaf(a.y,xv.x,y0.y));
        y1.x = fmaf(b.x,xv.x,fmaf(-b.y,xv.y,y1.x)); y1.y = fmaf(b.x,xv.y,fmaf(b.y,xv.x,y1.y));
      }
      part[(size_t)f*T_ + s*512 + tid] =
        make_float2(fmaf(y0.x,y0.x,y0.y*y0.y), fmaf(y1.x,y1.x,y1.y*y1.y));
    }
  }
  // ---- convergence ticket over all 513 blocks ----
  __threadfence();
  if (tid == 0) lastF = (atomicAdd(&flags[1], 1) == F_-1) ? 1 : 0;
  __syncthreads();
  if (lastF && tid < 64){
    __threadfence();
    double d=0, o=0;
    for (int idx=tid; idx<F_; idx+=64){
      d += ((volatile double*)dsum)[idx];
      o += ((volatile double*)osum)[idx];
    }
    for (int off=32; off; off>>=1){ d += __shfl_xor(d, off, 64); o += __shfl_xor(o, off, 64); }
    if (tid == 0){
      flags[1] = 0;
      double rel = sqrt(d) / fmax(sqrt(o), 1.1920928955078125e-7);
      if (rel < TOLC) flags[0] = 1;
    }
  }
}

__global__ __launch_bounds__(256) void scale_kernel(const float2* __restrict__ Wg, float2* __restrict__ scale){
  int f = blockIdx.x*256 + threadIdx.x;
  if (f >= F_) return;
  cd w0[8], w1[8];
  #pragma unroll
  for (int m=0;m<8;++m){
    float2 a = Wg[(size_t)f*64 + m];     w0[m] = cmk(a.x, a.y);
    float2 b = Wg[(size_t)f*64 + 8 + m]; w1[m] = cmk(b.x, b.y);
  }
  cd G00 = cmk(0,0), G01 = cmk(0,0), G11 = cmk(0,0);
  #pragma unroll
  for (int m=0;m<8;++m){
    G00 = cadd(G00, cmul(w0[m], cconj(w0[m])));
    G01 = cadd(G01, cmul(w0[m], cconj(w1[m])));
    G11 = cadd(G11, cmul(w1[m], cconj(w1[m])));
  }
  cd G10 = cconj(G01);
  cd det = csub(cmul(G00,G11), cmul(G01,G10));
  cd I00 = cdiv(G11, det), I01 = cdiv(cmk(-G01.x,-G01.y), det);
  cd I10 = cdiv(cmk(-G10.x,-G10.y), det), I11 = cdiv(G00, det);
  cd c0 = cconj(w0[0]), c1 = cconj(w1[0]);
  cd s0 = cadd(cmul(c0, I00), cmul(c1, I10));
  cd s1 = cadd(cmul(c0, I01), cmul(c1, I11));
  float2 o0; o0.x=(float)s0.x; o0.y=(float)s0.y;
  float2 o1; o1.x=(float)s1.x; o1.y=(float)s1.y;
  scale[(size_t)f*2 + 0] = o0;
  scale[(size_t)f*2 + 1] = o1;
}

// out (K,T,F,2) with scale, via LDS transpose. grid (17, 32)
__global__ __launch_bounds__(256) void out_kernel(const float2* __restrict__ Xc, const float2* __restrict__ Wg,
                                                  const float2* __restrict__ scale, float2* __restrict__ out){
  __shared__ float re0[32][65], im0[32][65], re1[32][65], im1[32][65];
  int f0 = blockIdx.x*32, t0 = blockIdx.y*64;
  int lane = threadIdx.x & 63, w = threadIdx.x >> 6;
  for (int fl = w; fl < 32; fl += 4){
    int f = f0 + fl;
    if (f < F_){
      const float2* Wf = Wg + (size_t)f*64;
      int t = t0 + lane;
      float2 y0; y0.x=0; y0.y=0;
      float2 y1; y1.x=0; y1.y=0;
      #pragma unroll
      for (int m=0;m<8;++m){
        float2 xv = Xc[((size_t)f*8 + m)*T_ + t];
        float2 w0 = Wf[m];
        float2 w1 = Wf[8+m];
        y0.x += w0.x*xv.x - w0.y*xv.y; y0.y += w0.x*xv.y + w0.y*xv.x;
        y1.x += w1.x*xv.x - w1.y*xv.y; y1.y += w1.x*xv.y + w1.y*xv.x;
      }
      float2 s0 = scale[(size_t)f*2 + 0];
      float2 s1 = scale[(size_t)f*2 + 1];
      re0[fl][lane] = s0.x*y0.x - s0.y*y0.y; im0[fl][lane] = s0.x*y0.y + s0.y*y0.x;
      re1[fl][lane] = s1.x*y1.x - s1.y*y1.y; im1[fl][lane] = s1.x*y1.y + s1.y*y1.x;
    }
  }
  __syncthreads();
  for (int i = threadIdx.x; i < 32*64; i += 256){
    int tl = i >> 5, fl = i & 31;
    int f = f0 + fl;
    if (f < F_){
      int t = t0 + tl;
      float2 o0; o0.x = re0[fl][tl]; o0.y = im0[fl][tl];
      float2 o1; o1.x = re1[fl][tl]; o1.y = im1[fl][tl];
      out[((size_t)(0*T_ + t))*F_ + f] = o0;
      out[((size_t)(1*T_ + t))*F_ + f] = o1;
    }
  }
}

extern "C" void kernel_launch(void* const* d_in, const int* in_sizes, int n_in,
                              void* d_out, int out_size, void* d_ws, size_t ws_size,
                              hipStream_t stream) {
  const float2* Xin = (const float2*)d_in[0];
  char* ws = (char*)d_ws;
  size_t off = 0;
  auto alloc = [&](size_t bytes) -> void* {
    void* p = ws + off;
    off += (bytes + 255) & ~(size_t)255;
    return p;
  };
  float2* Xc   = (float2*)alloc((size_t)F_*M_*T_*8);
  cd*     Cp   = (cd*)alloc((size_t)F_*TS*64*16);
  float2* W    = (float2*)alloc((size_t)F_*64*8);
  float2* part = (float2*)alloc((size_t)F_*T_*8);
  float2* wts2 = (float2*)alloc((size_t)T_*8);
  double* dsum = (double*)alloc((size_t)F_*8);
  double* osum = (double*)alloc((size_t)F_*8);
  float2* sc   = (float2*)alloc((size_t)F_*K_*8);
  int*    flags= (int*)alloc(256);
  if (off > ws_size) return;

  hipMemsetAsync(flags, 0, 12, stream);

  pack_kernel<<<dim3(9, 64, 8), 256, 0, stream>>>(Xin, Xc);
  winit_kernel<<<(F_*64 + 255)/256, 256, 0, stream>>>(W);
  cov0_kernel<<<dim3(F_, TS), 512, 0, stream>>>(Xc, Cp, part);

  for (int it=0; it<NITER; ++it){
    rw_kernel<<<32, 512, 0, stream>>>(part, wts2, flags);
    covupd_kernel<<<F_, 512, 0, stream>>>(Xc, wts2, Cp, W, part, dsum, osum, flags,
                                          (it < NITER-1) ? 1 : 0);
  }

  scale_kernel<<<(F_ + 255)/256, 256, 0, stream>>>(W, sc);
  out_kernel<<<dim3(17, 32), 256, 0, stream>>>(Xc, W, sc, (float2*)d_out);
}

// Round 8
// 1701.241 us; speedup vs baseline: 2.1493x; 2.1493x over previous
//
#include <hip/hip_runtime.h>
#include <hip/hip_cooperative_groups.h>

namespace cg = cooperative_groups;

#define F_ 513
#define M_ 8
#define T_ 2048
#define K_ 2
#define NITER 20
#define REGC 1e-6
#define EPSR 1e-10
#define TOLC 1e-5
#define NG 256
#define TS 4
#define UPB ((F_ + 3) / 4)
#define NBC 1024   // cooperative grid blocks

typedef double2 cd;
__device__ __forceinline__ cd cmk(double r, double i){ cd z; z.x=r; z.y=i; return z; }
__device__ __forceinline__ cd cadd(cd a, cd b){ return cmk(a.x+b.x, a.y+b.y); }
__device__ __forceinline__ cd csub(cd a, cd b){ return cmk(a.x-b.x, a.y-b.y); }
__device__ __forceinline__ cd cmul(cd a, cd b){ return cmk(a.x*b.x - a.y*b.y, a.x*b.y + a.y*b.x); }
__device__ __forceinline__ cd cconj(cd a){ return cmk(a.x, -a.y); }
__device__ __forceinline__ cd cdiv(cd a, cd b){
  double d = b.x*b.x + b.y*b.y;
  return cmk((a.x*b.x + a.y*b.y)/d, (a.y*b.x - a.x*b.y)/d);
}
__device__ __forceinline__ double cabs2(cd a){ return a.x*a.x + a.y*a.y; }
__device__ __forceinline__ cd shflc(cd v, int l){
  cd r; r.x = __shfl(v.x, l, 64); r.y = __shfl(v.y, l, 64); return r;
}
__device__ __forceinline__ cd sel8(const cd x[8], int idx){
  cd r = x[0];
  #pragma unroll
  for (int q=1;q<8;++q) if (idx==q) r = x[q];
  return r;
}

// ---- the per-f fp64 solve (wave-wide; lane=(i,j) of 8x8). Returns via Wg/dsum/osum. ----
__device__ __forceinline__ void solve_f(int f, int lane,
    const cd* __restrict__ Vp, const cd* __restrict__ Cp,
    float2* __restrict__ Wg, double* __restrict__ dsum, double* __restrict__ osum)
{
  int i = lane >> 3, j = lane & 7;
  float2 wf = Wg[(size_t)f*64 + lane];
  cd Wn = cmk(wf.x, wf.y);
  cd Wold = Wn;
  cd x[8];
  #pragma unroll
  for (int k=0; k<K_; ++k){
    cd Vr = cmk(0,0);
    #pragma unroll
    for (int s2=0; s2<TS; ++s2)
      Vr = cadd(Vr, Vp[(((size_t)k*F_ + f)*TS + s2)*64 + lane]);
    if (i == j) Vr.x += REGC;
    cd temp = cmk(0,0);
    #pragma unroll
    for (int q=0;q<8;++q) temp = cadd(temp, cmul(shflc(Wn, i*8+q), shflc(Vr, q*8+j)));
    cd b = cmk(i==k ? 1.0 : 0.0, 0.0);
    for (int p=0; p<8; ++p){
      double pv = (j==p && i>=p) ? cabs2(temp) : -1.0;
      int pidx = i;
      for (int off=32; off; off>>=1){
        double ov = __shfl_xor(pv, off, 64);
        int oi = __shfl_xor(pidx, off, 64);
        if (ov > pv){ pv = ov; pidx = oi; }
      }
      cd tp = shflc(temp, pidx*8 + j);
      cd tq = shflc(temp, p*8 + j);
      cd bp_ = shflc(b, pidx*8 + j);
      cd bq_ = shflc(b, p*8 + j);
      if (i == p){ temp = tp; b = bp_; }
      else if (i == pidx){ temp = tq; b = bq_; }
      cd tip = shflc(temp, i*8 + p);
      cd tpp = shflc(temp, p*8 + p);
      cd tpj = shflc(temp, p*8 + j);
      cd bpr = shflc(b, p*8 + j);
      cd fac = cdiv(tip, tpp);
      if (i > p){ temp = csub(temp, cmul(fac, tpj)); b = csub(b, cmul(fac, bpr)); }
    }
    #pragma unroll
    for (int p=7; p>=0; --p){
      cd s = shflc(b, p*8);
      #pragma unroll
      for (int q=p+1; q<8; ++q){
        cd tpq = shflc(temp, p*8 + q);
        s = csub(s, cmul(tpq, x[q]));
      }
      x[p] = cdiv(s, shflc(temp, p*8 + p));
    }
    cd xi = sel8(x, i), xj = sel8(x, j);
    cd z = cmul(cconj(xi), Vr);
    double dl = z.x*xj.x - z.y*xj.y;
    for (int off=32; off; off>>=1) dl += __shfl_xor(dl, off, 64);
    double denom = sqrt(dl + EPSR);
    if (i == k){ Wn = cmk(xj.x/denom, -xj.y/denom); }
  }
  cd Cc = cmk(0,0);
  #pragma unroll
  for (int s2=0; s2<TS; ++s2)
    Cc = cadd(Cc, Cp[((size_t)f*TS + s2)*64 + lane]);
  cd tmp = cmk(0,0);
  #pragma unroll
  for (int q=0;q<8;++q) tmp = cadd(tmp, cmul(shflc(Wn, i*8+q), shflc(Cc, q*8+j)));
  cd A = shflc(tmp, 0), B = shflc(tmp, 1), C2 = shflc(tmp, 8), D = shflc(tmp, 9);
  cd det = csub(cmul(A,D), cmul(B,C2));
  cd t0 = shflc(tmp, i);
  cd t1 = shflc(tmp, 8 + i);
  cd Z0 = cdiv(csub(cmul(D,t0), cmul(B,t1)), det);
  cd Z1 = cdiv(csub(cmul(A,t1), cmul(C2,t0)), det);
  if (i >= K_ && j < K_){
    cd Z = (j==0) ? Z0 : Z1;
    Wn = cconj(Z);
  }
  double ds = cabs2(csub(Wn, Wold));
  double os = cabs2(Wold);
  for (int off=32; off; off>>=1){
    ds += __shfl_xor(ds, off, 64);
    os += __shfl_xor(os, off, 64);
  }
  float2 wo; wo.x = (float)Wn.x; wo.y = (float)Wn.y;
  Wg[(size_t)f*64 + lane] = wo;
  if (lane == 0){ dsum[f] = ds; osum[f] = os; }
}

// ================= cooperative whole-loop kernel =================
// grid NBC x 256. Tiles (f,s): tile = f*4+s, 2052 total. Block b: {2b, 2b+1, 2048+b if b<4}.
__global__ __launch_bounds__(256, 4) void iva_loop_kernel(
    const float2* __restrict__ Xc, const cd* __restrict__ Cp,
    float2* __restrict__ Wg, float2* __restrict__ partF,
    float2* __restrict__ wts2, cd* __restrict__ Vp,
    double* __restrict__ dsum, double* __restrict__ osum,
    int* __restrict__ flags, int* __restrict__ tickf)
{
  cg::grid_group grid = cg::this_grid();
  __shared__ float2 xbuf[8][132];
  __shared__ float wredV[4][4][64];
  __shared__ double wredR[4][64][2];
  __shared__ int solvN;
  __shared__ int solvF[4];
  int bid = blockIdx.x;
  int tid = threadIdx.x;
  int w = tid >> 6, lane = tid & 63;
  int m = lane >> 3, n = lane & 7;
  int tiles[3];
  tiles[0] = 2*bid; tiles[1] = 2*bid+1; tiles[2] = (bid < 4) ? 2048 + bid : -1;

  for (int it = 0; it < NITER; ++it){
    // ===== phase YR: partF[f][t] = (|y0|^2,|y1|^2) with current W =====
    #pragma unroll 1
    for (int sel = 0; sel < 3; ++sel){
      int tile = tiles[sel];
      if (tile < 0) continue;
      int f = tile >> 2, s = tile & 3;
      const float2* Wf = Wg + (size_t)f*64;
      float2 w0f[8], w1f[8];
      #pragma unroll
      for (int mm=0; mm<8; ++mm){ w0f[mm] = Wf[mm]; w1f[mm] = Wf[8+mm]; }
      int t = s*512 + tid*2;
      float2 y00={0,0}, y01={0,0}, y10={0,0}, y11={0,0};
      #pragma unroll
      for (int mm=0; mm<8; ++mm){
        float4 xv = *(const float4*)&Xc[((size_t)f*8+mm)*T_ + t];
        float2 a = w0f[mm], b2 = w1f[mm];
        y00.x = fmaf(a.x,xv.x,fmaf(-a.y,xv.y,y00.x)); y00.y = fmaf(a.x,xv.y,fmaf(a.y,xv.x,y00.y));
        y10.x = fmaf(b2.x,xv.x,fmaf(-b2.y,xv.y,y10.x)); y10.y = fmaf(b2.x,xv.y,fmaf(b2.y,xv.x,y10.y));
        y01.x = fmaf(a.x,xv.z,fmaf(-a.y,xv.w,y01.x)); y01.y = fmaf(a.x,xv.w,fmaf(a.y,xv.z,y01.y));
        y11.x = fmaf(b2.x,xv.z,fmaf(-b2.y,xv.w,y11.x)); y11.y = fmaf(b2.x,xv.w,fmaf(b2.y,xv.z,y11.y));
      }
      float4 pr;
      pr.x = fmaf(y00.x,y00.x,y00.y*y00.y);
      pr.y = fmaf(y10.x,y10.x,y10.y*y10.y);
      pr.z = fmaf(y01.x,y01.x,y01.y*y01.y);
      pr.w = fmaf(y11.x,y11.x,y11.y*y11.y);
      *(float4*)&partF[(size_t)f*T_ + t] = pr;
    }
    __threadfence();
    grid.sync();
    // ===== phase RW (blocks 0..31): wts2[t] =====
    if (bid < 32){
      int t = bid*64 + lane;
      double s0=0, s1=0;
      for (int f=w; f<F_; f+=4){
        float2 p = partF[(size_t)f*T_ + t];
        s0 += (double)p.x; s1 += (double)p.y;
      }
      wredR[w][lane][0]=s0; wredR[w][lane][1]=s1;
      __syncthreads();
      if (tid < 64){
        double a=0,b2=0;
        #pragma unroll
        for (int ww=0; ww<4; ++ww){ a += wredR[ww][tid][0]; b2 += wredR[ww][tid][1]; }
        wts2[bid*64+tid] = make_float2((float)(0.5/sqrt(fmax(a,EPSR))),
                                       (float)(0.5/sqrt(fmax(b2,EPSR))));
      }
      __threadfence();
    }
    grid.sync();
    // ===== phase V (+ inline per-f solve via ticket) =====
    if (tid == 0) solvN = 0;
    __syncthreads();
    #pragma unroll 1
    for (int sel = 0; sel < 3; ++sel){
      int tile = tiles[sel];
      if (tile < 0) continue;
      int f = tile >> 2, s = tile & 3;
      float a0r=0.f, a0i=0.f, a1r=0.f, a1i=0.f;
      #pragma unroll 1
      for (int c=0; c<4; ++c){
        __syncthreads();
        #pragma unroll
        for (int r=0; r<2; ++r){
          int idx = tid + r*256;           // 512 float4 = 8 rows x 64
          int mm = idx >> 6, q = idx & 63;
          float4 v = *(const float4*)&Xc[((size_t)f*8+mm)*T_ + s*512 + c*128 + q*2];
          *(float4*)&xbuf[mm][q*2] = v;
        }
        __syncthreads();
        const float2* xm = xbuf[m];
        const float2* xn = xbuf[n];
        int tb = w*32;
        #pragma unroll
        for (int tt=0; tt<32; tt+=2){
          float4 av = *(const float4*)&xm[tb+tt];
          float4 bv = *(const float4*)&xn[tb+tt];
          float zr0 = fmaf(av.x,bv.x, av.y*bv.y);
          float zi0 = fmaf(av.y,bv.x,-av.x*bv.y);
          float zr1 = fmaf(av.z,bv.z, av.w*bv.w);
          float zi1 = fmaf(av.w,bv.z,-av.z*bv.w);
          float4 wv = *(const float4*)&wts2[s*512 + c*128 + tb + tt];
          a0r = fmaf(wv.x, zr0, a0r); a0i = fmaf(wv.x, zi0, a0i);
          a1r = fmaf(wv.y, zr0, a1r); a1i = fmaf(wv.y, zi0, a1i);
          a0r = fmaf(wv.z, zr1, a0r); a0i = fmaf(wv.z, zi1, a0i);
          a1r = fmaf(wv.w, zr1, a1r); a1i = fmaf(wv.w, zi1, a1i);
        }
      }
      __syncthreads();
      wredV[0][w][lane]=a0r; wredV[1][w][lane]=a0i;
      wredV[2][w][lane]=a1r; wredV[3][w][lane]=a1i;
      __syncthreads();
      if (tid < 128){
        int k = tid >> 6, l = tid & 63;
        float rr=0.f, ii=0.f;
        #pragma unroll
        for (int ww=0; ww<4; ++ww){ rr += wredV[2*k][ww][l]; ii += wredV[2*k+1][ww][l]; }
        const double inv = 1.0/(double)T_;
        Vp[(((size_t)k*F_+f)*TS + s)*64 + l] = cmk((double)rr*inv, (double)ii*inv);
      }
      __threadfence();
      __syncthreads();
      if (tid == 0){
        int tk = atomicAdd(&tickf[f], 1);
        if (tk == TS-1){
          tickf[f] = 0;
          solvF[solvN] = f;
          solvN = solvN + 1;
        }
      }
    }
    __syncthreads();
    int ns = solvN;
    if (w < ns){
      int f = solvF[w];
      solve_f(f, lane, Vp, Cp, Wg, dsum, osum);
      int lastw = 0;
      if (lane == 0){
        __threadfence();
        lastw = (atomicAdd(&flags[1], 1) == F_-1) ? 1 : 0;
      }
      lastw = __shfl(lastw, 0, 64);
      if (lastw){
        __threadfence();
        double d=0, o=0;
        for (int idx=lane; idx<F_; idx+=64){
          d += ((volatile double*)dsum)[idx];
          o += ((volatile double*)osum)[idx];
        }
        for (int off=32; off; off>>=1){ d += __shfl_xor(d, off, 64); o += __shfl_xor(o, off, 64); }
        if (lane == 0){
          flags[1] = 0;
          double rel = sqrt(d) / fmax(sqrt(o), 1.1920928955078125e-7);
          if (rel < TOLC) flags[0] = 1;
        }
      }
    }
    __threadfence();
    grid.sync();
    if (*(volatile int*)&flags[0]) break;
  }
}

// ================= standard kernels =================

// pack X (M,T,F,2) -> Xc (F,M,T) complex; 64f x 32t LDS tile
__global__ __launch_bounds__(256) void pack_kernel(const float2* __restrict__ Xin, float2* __restrict__ Xc){
  __shared__ float tr[32][65];
  __shared__ float ti[32][65];
  int f0 = blockIdx.x*64, t0 = blockIdx.y*32, m = blockIdx.z;
  for (int i = threadIdx.x; i < 32*64; i += 256){
    int tl = i >> 6, fl = i & 63;
    int f = f0 + fl;
    float2 v; v.x = 0.f; v.y = 0.f;
    if (f < F_) v = Xin[((size_t)m*T_ + (t0 + tl))*F_ + f];
    tr[tl][fl] = v.x; ti[tl][fl] = v.y;
  }
  __syncthreads();
  for (int i = threadIdx.x; i < 64*16; i += 256){
    int fl = i >> 4, tl2 = i & 15;
    int f = f0 + fl;
    if (f < F_){
      int t = 2*tl2;
      float4 v;
      v.x = tr[t][fl];   v.y = ti[t][fl];
      v.z = tr[t+1][fl]; v.w = ti[t+1][fl];
      *(float4*)&Xc[((size_t)f*8 + m)*T_ + t0 + t] = v;
    }
  }
}

__global__ __launch_bounds__(256) void winit_kernel(float2* __restrict__ W){
  int idx = blockIdx.x*256 + threadIdx.x;
  if (idx >= F_*64) return;
  int l = idx & 63; int i = l>>3, j = l&7;
  float v = (i==j) ? (i < K_ ? 1.f : -1.f) : 0.f;
  float2 o; o.x = v; o.y = 0.f;
  W[idx] = o;
}

// C chunk partials. grid (F,TS), 512 thr.
__global__ __launch_bounds__(512) void cov0_kernel(const float2* __restrict__ Xc, cd* __restrict__ Cp){
  __shared__ float2 xs[8][514];
  __shared__ double wred[2][8][64];
  int f = blockIdx.x, s = blockIdx.y;
  int tid = threadIdx.x;
  int w = tid >> 6, lane = tid & 63;
  int m = lane >> 3, n = lane & 7;
  #pragma unroll
  for (int r=0; r<4; ++r){
    int idx = tid + r*512;
    int mm = idx >> 8, q = idx & 255;
    float4 v = ((const float4*)(Xc + ((size_t)f*8 + mm)*T_ + s*512))[q];
    *(float4*)&xs[mm][q*2] = v;
  }
  __syncthreads();
  const float2* xm = xs[m];
  const float2* xn = xs[n];
  int tbase = w*64;
  float ar=0.f, ai=0.f;
  #pragma unroll 8
  for (int tt=0; tt<64; tt+=2){
    float4 av = *(const float4*)&xm[tbase+tt];
    float4 bv = *(const float4*)&xn[tbase+tt];
    ar += fmaf(av.x, bv.x, av.y*bv.y) + fmaf(av.z, bv.z, av.w*bv.w);
    ai += fmaf(av.y, bv.x, -av.x*bv.y) + fmaf(av.w, bv.z, -av.z*bv.w);
  }
  wred[0][w][lane] = ar; wred[1][w][lane] = ai;
  __syncthreads();
  if (tid < 64){
    double sr=0, si=0;
    #pragma unroll
    for (int ww=0; ww<8; ++ww){ sr += wred[0][ww][tid]; si += wred[1][ww][tid]; }
    const double inv = 1.0/(double)T_;
    Cp[((size_t)f*TS + s)*64 + tid] = cmk(sr*inv, si*inv);
  }
}

// ---------- fallback (R6) loop kernels ----------
__global__ __launch_bounds__(256) void yrF_kernel(const float2* __restrict__ Xc, const float2* __restrict__ Wg,
                                                  float* __restrict__ part, const int* __restrict__ flags){
  if (*(volatile const int*)flags) return;
  int g = blockIdx.y;
  int t = blockIdx.x*256 + threadIdx.x;
  float acc0 = 0.f, acc1 = 0.f;
  for (int f = g; f < F_; f += NG){
    const float2* Wf = Wg + (size_t)f*64;
    float2 y0; y0.x=0; y0.y=0;
    float2 y1; y1.x=0; y1.y=0;
    #pragma unroll
    for (int m=0;m<8;++m){
      float2 xv = Xc[((size_t)f*8 + m)*T_ + t];
      float2 w0 = Wf[m];
      float2 w1 = Wf[8+m];
      y0.x = fmaf(w0.x,xv.x,fmaf(-w0.y,xv.y,y0.x)); y0.y = fmaf(w0.x,xv.y,fmaf(w0.y,xv.x,y0.y));
      y1.x = fmaf(w1.x,xv.x,fmaf(-w1.y,xv.y,y1.x)); y1.y = fmaf(w1.x,xv.y,fmaf(w1.y,xv.x,y1.y));
    }
    acc0 += y0.x*y0.x + y0.y*y0.y;
    acc1 += y1.x*y1.x + y1.y*y1.y;
  }
  part[((size_t)g*2+0)*T_ + t] = acc0;
  part[((size_t)g*2+1)*T_ + t] = acc1;
}

__global__ __launch_bounds__(256) void rwF_kernel(const float* __restrict__ part, float* __restrict__ wts2f,
                                                  const int* __restrict__ flags){
  if (*(volatile const int*)flags) return;
  int v = blockIdx.x*256 + threadIdx.x;
  int k = v >> 11, t = v & (T_-1);
  double s = 0;
  for (int g=0; g<NG; ++g) s += (double)part[((size_t)g*2+k)*T_ + t];
  wts2f[2*t + k] = (float)(0.5 / sqrt(fmax(s, EPSR)));
}

__global__ __launch_bounds__(512, 8) void covF_kernel(const float2* __restrict__ Xc, const float2* __restrict__ wts2,
                                                      cd* __restrict__ outP, const int* __restrict__ flags){
  if (*(volatile const int*)flags) return;
  __shared__ float2 xs[8][514];
  __shared__ float2 wsm2[512];
  int f = blockIdx.x, s = blockIdx.y;
  int tid = threadIdx.x;
  int w = tid >> 6, lane = tid & 63;
  int m = lane >> 3, n = lane & 7;
  #pragma unroll
  for (int r=0; r<4; ++r){
    int idx = tid + r*512;
    int mm = idx >> 8, q = idx & 255;
    float4 v = ((const float4*)(Xc + ((size_t)f*8 + mm)*T_ + s*512))[q];
    *(float4*)&xs[mm][q*2] = v;
  }
  wsm2[tid] = wts2[s*512 + tid];
  __syncthreads();
  const float2* xm = xs[m];
  const float2* xn = xs[n];
  int tbase = w*64;
  float a0r=0.f, a0i=0.f, a1r=0.f, a1i=0.f;
  #pragma unroll 8
  for (int tt=0; tt<64; tt+=2){
    float4 av = *(const float4*)&xm[tbase+tt];
    float4 bv = *(const float4*)&xn[tbase+tt];
    float zr0 = fmaf(av.x, bv.x, av.y*bv.y);
    float zi0 = fmaf(av.y, bv.x, -av.x*bv.y);
    float zr1 = fmaf(av.z, bv.z, av.w*bv.w);
    float zi1 = fmaf(av.w, bv.z, -av.z*bv.w);
    float4 wv = *(const float4*)&wsm2[tbase+tt];
    a0r = fmaf(wv.x, zr0, a0r); a0i = fmaf(wv.x, zi0, a0i);
    a1r = fmaf(wv.y, zr0, a1r); a1i = fmaf(wv.y, zi0, a1i);
    a0r = fmaf(wv.z, zr1, a0r); a0i = fmaf(wv.z, zi1, a0i);
    a1r = fmaf(wv.w, zr1, a1r); a1i = fmaf(wv.w, zi1, a1i);
  }
  __syncthreads();
  float* wred = (float*)&xs[0][0];
  wred[0*512 + w*64 + lane] = a0r;
  wred[1*512 + w*64 + lane] = a0i;
  wred[2*512 + w*64 + lane] = a1r;
  wred[3*512 + w*64 + lane] = a1i;
  __syncthreads();
  const double inv = 1.0/(double)T_;
  if (tid < 128){
    int k = tid >> 6, l = tid & 63;
    float rr = 0.f, ii = 0.f;
    #pragma unroll
    for (int ww=0; ww<8; ++ww){
      rr += wred[(k*2+0)*512 + ww*64 + l];
      ii += wred[(k*2+1)*512 + ww*64 + l];
    }
    outP[(((size_t)k*F_ + f)*TS + s)*64 + l] = cmk((double)rr*inv, (double)ii*inv);
  }
}

__global__ __launch_bounds__(256) void updF_kernel(const cd* __restrict__ Vp, const cd* __restrict__ Cp,
                                                   float2* __restrict__ Wg,
                                                   double* __restrict__ dsum, double* __restrict__ osum,
                                                   int* __restrict__ flags){
  if (*(volatile const int*)flags) return;
  int lane = threadIdx.x & 63;
  int w = threadIdx.x >> 6;
  int f = blockIdx.x*4 + w;
  if (f < F_) solve_f(f, lane, Vp, Cp, Wg, dsum, osum);
  __shared__ int lastFlag;
  __threadfence();
  __syncthreads();
  if (threadIdx.x == 0){
    int tk = atomicAdd(&flags[1], 1);
    lastFlag = (tk == UPB-1) ? 1 : 0;
  }
  __syncthreads();
  if (lastFlag && threadIdx.x < 64){
    __threadfence();
    double d=0, o=0;
    for (int idx=lane; idx<F_; idx+=64){
      d += ((volatile double*)dsum)[idx];
      o += ((volatile double*)osum)[idx];
    }
    for (int off=32; off; off>>=1){ d += __shfl_xor(d, off, 64); o += __shfl_xor(o, off, 64); }
    if (lane == 0){
      flags[1] = 0;
      double rel = sqrt(d) / fmax(sqrt(o), 1.1920928955078125e-7);
      if (rel < TOLC) flags[0] = 1;
    }
  }
}

__global__ __launch_bounds__(256) void scale_kernel(const float2* __restrict__ Wg, float2* __restrict__ scale){
  int f = blockIdx.x*256 + threadIdx.x;
  if (f >= F_) return;
  cd w0[8], w1[8];
  #pragma unroll
  for (int m=0;m<8;++m){
    float2 a = Wg[(size_t)f*64 + m];     w0[m] = cmk(a.x, a.y);
    float2 b = Wg[(size_t)f*64 + 8 + m]; w1[m] = cmk(b.x, b.y);
  }
  cd G00 = cmk(0,0), G01 = cmk(0,0), G11 = cmk(0,0);
  #pragma unroll
  for (int m=0;m<8;++m){
    G00 = cadd(G00, cmul(w0[m], cconj(w0[m])));
    G01 = cadd(G01, cmul(w0[m], cconj(w1[m])));
    G11 = cadd(G11, cmul(w1[m], cconj(w1[m])));
  }
  cd G10 = cconj(G01);
  cd det = csub(cmul(G00,G11), cmul(G01,G10));
  cd I00 = cdiv(G11, det), I01 = cdiv(cmk(-G01.x,-G01.y), det);
  cd I10 = cdiv(cmk(-G10.x,-G10.y), det), I11 = cdiv(G00, det);
  cd c0 = cconj(w0[0]), c1 = cconj(w1[0]);
  cd s0 = cadd(cmul(c0, I00), cmul(c1, I10));
  cd s1 = cadd(cmul(c0, I01), cmul(c1, I11));
  float2 o0; o0.x=(float)s0.x; o0.y=(float)s0.y;
  float2 o1; o1.x=(float)s1.x; o1.y=(float)s1.y;
  scale[(size_t)f*2 + 0] = o0;
  scale[(size_t)f*2 + 1] = o1;
}

__global__ __launch_bounds__(256) void out_kernel(const float2* __restrict__ Xc, const float2* __restrict__ Wg,
                                                  const float2* __restrict__ scale, float2* __restrict__ out){
  __shared__ float re0[32][65], im0[32][65], re1[32][65], im1[32][65];
  int f0 = blockIdx.x*32, t0 = blockIdx.y*64;
  int lane = threadIdx.x & 63, w = threadIdx.x >> 6;
  for (int fl = w; fl < 32; fl += 4){
    int f = f0 + fl;
    if (f < F_){
      const float2* Wf = Wg + (size_t)f*64;
      int t = t0 + lane;
      float2 y0; y0.x=0; y0.y=0;
      float2 y1; y1.x=0; y1.y=0;
      #pragma unroll
      for (int m=0;m<8;++m){
        float2 xv = Xc[((size_t)f*8 + m)*T_ + t];
        float2 w0 = Wf[m];
        float2 w1 = Wf[8+m];
        y0.x += w0.x*xv.x - w0.y*xv.y; y0.y += w0.x*xv.y + w0.y*xv.x;
        y1.x += w1.x*xv.x - w1.y*xv.y; y1.y += w1.x*xv.y + w1.y*xv.x;
      }
      float2 s0 = scale[(size_t)f*2 + 0];
      float2 s1 = scale[(size_t)f*2 + 1];
      re0[fl][lane] = s0.x*y0.x - s0.y*y0.y; im0[fl][lane] = s0.x*y0.y + s0.y*y0.x;
      re1[fl][lane] = s1.x*y1.x - s1.y*y1.y; im1[fl][lane] = s1.x*y1.y + s1.y*y1.x;
    }
  }
  __syncthreads();
  for (int i = threadIdx.x; i < 32*64; i += 256){
    int tl = i >> 5, fl = i & 31;
    int f = f0 + fl;
    if (f < F_){
      int t = t0 + tl;
      float2 o0; o0.x = re0[fl][tl]; o0.y = im0[fl][tl];
      float2 o1; o1.x = re1[fl][tl]; o1.y = im1[fl][tl];
      out[((size_t)(0*T_ + t))*F_ + f] = o0;
      out[((size_t)(1*T_ + t))*F_ + f] = o1;
    }
  }
}

extern "C" void kernel_launch(void* const* d_in, const int* in_sizes, int n_in,
                              void* d_out, int out_size, void* d_ws, size_t ws_size,
                              hipStream_t stream) {
  const float2* Xin = (const float2*)d_in[0];
  char* ws = (char*)d_ws;
  size_t off = 0;
  auto alloc = [&](size_t bytes) -> void* {
    void* p = ws + off;
    off += (bytes + 255) & ~(size_t)255;
    return p;
  };
  float2* Xc    = (float2*)alloc((size_t)F_*M_*T_*8);
  cd*     Cp    = (cd*)alloc((size_t)F_*TS*64*16);
  cd*     Vp    = (cd*)alloc((size_t)K_*F_*TS*64*16);
  float2* W     = (float2*)alloc((size_t)F_*64*8);
  float2* partF = (float2*)alloc((size_t)F_*T_*8);
  float*  partG = (float*)alloc((size_t)NG*K_*T_*4);
  float2* wts2  = (float2*)alloc((size_t)T_*8);
  double* dsum  = (double*)alloc((size_t)F_*8);
  double* osum  = (double*)alloc((size_t)F_*8);
  float2* sc    = (float2*)alloc((size_t)F_*K_*8);
  int*    ibuf  = (int*)alloc(4096);      // flags (256 ints) + tickf (513 ints)
  if (off > ws_size) return;
  int* flags = ibuf;
  int* tickf = ibuf + 256;

  hipMemsetAsync(ibuf, 0, 4096, stream);

  pack_kernel<<<dim3(9, 64, 8), 256, 0, stream>>>(Xin, Xc);
  winit_kernel<<<(F_*64 + 255)/256, 256, 0, stream>>>(W);
  cov0_kernel<<<dim3(F_, TS), 512, 0, stream>>>(Xc, Cp);

  // try the cooperative whole-loop kernel; fall back to the R6 pipeline on any failure
  bool coop_ok = false;
  int mb = 0;
  hipError_t e0 = hipOccupancyMaxActiveBlocksPerMultiprocessor(
      &mb, reinterpret_cast<const void*>(iva_loop_kernel), 256, 0);
  if (e0 == hipSuccess && mb >= 4){
    void* args[] = { (void*)&Xc, (void*)&Cp, (void*)&W, (void*)&partF, (void*)&wts2,
                     (void*)&Vp, (void*)&dsum, (void*)&osum, (void*)&flags, (void*)&tickf };
    hipError_t e1 = hipLaunchCooperativeKernel(
        reinterpret_cast<const void*>(iva_loop_kernel),
        dim3(NBC), dim3(256), args, 0, stream);
    if (e1 == hipSuccess) coop_ok = true;
  }
  if (!coop_ok){
    for (int it=0; it<NITER; ++it){
      yrF_kernel<<<dim3(T_/256, NG), 256, 0, stream>>>(Xc, W, partG, flags);
      rwF_kernel<<<(K_*T_ + 255)/256, 256, 0, stream>>>(partG, (float*)wts2, flags);
      covF_kernel<<<dim3(F_, TS), 512, 0, stream>>>(Xc, wts2, Vp, flags);
      updF_kernel<<<UPB, 256, 0, stream>>>(Vp, Cp, W, dsum, osum, flags);
    }
  }

  scale_kernel<<<(F_ + 255)/256, 256, 0, stream>>>(W, sc);
  out_kernel<<<dim3(17, 32), 256, 0, stream>>>(Xc, W, sc, (float2*)d_out);
}